// Round 4
// baseline (329.394 us; speedup 1.0000x reference)
//
#include <hip/hip_runtime.h>

#define HH 128
#define WW 128
#define HWSZ (HH * WW)
#define CC 64
#define OO 64
#define BB 4
#define NOFF 18
#define KK 576          // C*9
#define K2 288          // KK/2 (bf16 pairs)

// ws layout (float offsets)
#define WS_BG     0                         // 288*64 dwords = 18432 (deform weights, permuted K)
#define WS_BGOFF  18432                     // 288*32 dwords = 9216  (offset weights, flat K, padded N=32)
#define WS_SUMS   47232                     // 64
#define WS_SUMSQ  47296                     // 64
#define WS_OFFBUF 47360                     // 4*18*16384 = 1179648
#define WS_YBUF   1227008                   // 4*64*16384 = 4194304

typedef __attribute__((ext_vector_type(8))) short short8;
typedef __attribute__((ext_vector_type(4))) int int4v;
typedef __attribute__((ext_vector_type(4))) float f32x4;

__device__ inline unsigned bf16rne(float f) {
  unsigned u = __float_as_uint(f);
  u += 0x7fff + ((u >> 16) & 1);   // round-to-nearest-even (finite inputs)
  return u >> 16;
}

// Bg  (deform): [288][64] dwords. K-pair order permuted for the half-split:
//   k2n = h*144 + cg*36 + m  <->  flat pair f = cg*72 + h*36 + m
//   (wave cg, half h covers channels 16cg+8h .. +8; within-block flat k is contiguous)
// Bgo (offset): [288][32] dwords, flat K-pair order, o>=18 zero-padded.
__global__ __launch_bounds__(256) void prep_w_kernel(
    const float* __restrict__ off_w, const float* __restrict__ dc_w,
    int* __restrict__ Bg, int* __restrict__ Bgo) {
  int tid = blockIdx.x * 256 + threadIdx.x;
  int stride = gridDim.x * 256;
  for (int i = tid; i < K2 * OO; i += stride) {
    int k2n = i >> 6;
    int o = i & 63;
    int h = k2n / 144, r = k2n % 144;
    int f = (r / 36) * 72 + h * 36 + (r % 36);
    unsigned lo = bf16rne(dc_w[o * KK + 2 * f]);
    unsigned hi = bf16rne(dc_w[o * KK + 2 * f + 1]);
    Bg[i] = (int)(lo | (hi << 16));
  }
  for (int i = tid; i < K2 * 32; i += stride) {
    int k2 = i >> 5;
    int o = i & 31;
    unsigned pk = 0;
    if (o < NOFF) {
      unsigned lo = bf16rne(off_w[o * KK + 2 * k2]);
      unsigned hi = bf16rne(off_w[o * KK + 2 * k2 + 1]);
      pk = lo | (hi << 16);
    }
    Bgo[i] = (int)pk;
  }
}

// Offset conv as im2col + MFMA. Block = 64 px (half row) x 4 waves.
// Wave cg stages channels [16cg,16cg+16) x 9 taps (coalesced, zero-padded)
// into A_lds[k2][px], then MFMA vs Bgo (N=32, o>=18 dead).
__global__ __launch_bounds__(256) void offset_mfma_kernel(
    const float* __restrict__ x, const int* __restrict__ Bgo,
    const float* __restrict__ off_b, float* __restrict__ offbuf) {
  __shared__ int A_lds[K2 * 64];   // 72 KB

  int cg = threadIdx.x >> 6;
  int lane = threadIdx.x & 63;
  int b = blockIdx.x >> 8;
  int rem = blockIdx.x & 255;
  int h = rem >> 1;
  int w0 = (rem & 1) * 64;
  int hw0 = h * WW + w0;
  int w = w0 + lane;

  const float* xb = x + (b * CC + cg * 16) * HWSZ;
#pragma unroll 1
  for (int c16 = 0; c16 < 16; c16 += 2) {
    const float* xp0 = xb + c16 * HWSZ;
    const float* xp1 = xp0 + HWSZ;
    float s2[18];
#pragma unroll
    for (int ky = 0; ky < 3; ++ky) {
      int yy = h + ky - 1;
      bool oky = (yy >= 0) && (yy < HH);
      int cy = min(max(yy, 0), HH - 1);
#pragma unroll
      for (int kx = 0; kx < 3; ++kx) {
        int xx = w + kx - 1;
        bool ok = oky && (xx >= 0) && (xx < WW);
        int cx = min(max(xx, 0), WW - 1);
        int t = ky * 3 + kx;
        float v0 = xp0[cy * WW + cx];
        float v1 = xp1[cy * WW + cx];
        s2[t] = ok ? v0 : 0.0f;
        s2[9 + t] = ok ? v1 : 0.0f;
      }
    }
    int k2base = cg * 72 + (c16 * 9) / 2;
#pragma unroll
    for (int j = 0; j < 9; ++j) {
      unsigned pk = bf16rne(s2[2 * j]) | (bf16rne(s2[2 * j + 1]) << 16);
      A_lds[(k2base + j) * 64 + lane] = (int)pk;
    }
  }
  __syncthreads();

  int n16 = lane & 15;
  int q = lane >> 4;
  int mrow = cg * 16 + n16;
  const int* Bp = Bgo + q * 128 + n16;   // (q*4)*32 + n16
  f32x4 acc[2] = {f32x4{0,0,0,0}, f32x4{0,0,0,0}};
#pragma unroll 1
  for (int kk = 0; kk < 18; ++kk) {
    int abase = (kk * 16 + q * 4) * 64 + mrow;
    int4v av;
    av.x = A_lds[abase];
    av.y = A_lds[abase + 64];
    av.z = A_lds[abase + 128];
    av.w = A_lds[abase + 192];
    short8 af = __builtin_bit_cast(short8, av);
    const int* bp = Bp + kk * 512;
#pragma unroll
    for (int nt = 0; nt < 2; ++nt) {
      int4v bv;
      bv.x = bp[nt * 16];
      bv.y = bp[nt * 16 + 32];
      bv.z = bp[nt * 16 + 64];
      bv.w = bp[nt * 16 + 96];
      short8 bfr = __builtin_bit_cast(short8, bv);
      acc[nt] = __builtin_amdgcn_mfma_f32_16x16x32_bf16(af, bfr, acc[nt], 0, 0, 0);
    }
  }

#pragma unroll
  for (int nt = 0; nt < 2; ++nt) {
    int o = nt * 16 + n16;
    if (o < NOFF) {
      float bv = off_b[o];
      float* ob = offbuf + (size_t)(b * NOFF + o) * HWSZ + hw0 + cg * 16 + q * 4;
#pragma unroll
      for (int r = 0; r < 4; ++r) ob[r] = acc[nt][r] + bv;
    }
  }
}

// Deform conv: im2col gather + MFMA, K split into 2 halves of 288 so
// A_lds is 36 KB -> 4 blocks/CU (was 72 KB -> 2).
__global__ __launch_bounds__(256, 4) void deform_mfma_kernel(
    const float* __restrict__ x, const float* __restrict__ offbuf,
    const int* __restrict__ Bg, const float* __restrict__ dc_b,
    float* __restrict__ ybuf) {
  __shared__ int A_lds[(K2 / 2) * 64];   // 36864 B

  int cg = threadIdx.x >> 6;
  int lane = threadIdx.x & 63;
  int b = blockIdx.x >> 8;
  int rem = blockIdx.x & 255;
  int h = rem >> 1;
  int w0 = (rem & 1) * 64;
  int hw0 = h * WW + w0;
  int hw = hw0 + lane;
  int w = w0 + lane;

  // ---- bilinear meta for 9 taps at px = lane ----
  int base00[9], base01[9], base10[9], base11[9];
  float wt00[9], wt01[9], wt10[9], wt11[9];
  const float* ob = offbuf + b * NOFF * HWSZ + hw;
#pragma unroll
  for (int k = 0; k < 9; ++k) {
    float dy = ob[(2 * k) * HWSZ];
    float dx = ob[(2 * k + 1) * HWSZ];
    float py = (float)(h + (k / 3) - 1) + dy;
    float px = (float)(w + (k % 3) - 1) + dx;
    float fy0 = floorf(py), fx0 = floorf(px);
    float ay = py - fy0, ax = px - fx0;
    int iy0 = (int)fy0, ix0 = (int)fx0;
    int iy1 = iy0 + 1, ix1 = ix0 + 1;
    float wy0 = 1.0f - ay, wy1 = ay, wx0 = 1.0f - ax, wx1 = ax;
    if (!(iy0 >= 0 && iy0 < HH)) wy0 = 0.0f;
    if (!(iy1 >= 0 && iy1 < HH)) wy1 = 0.0f;
    if (!(ix0 >= 0 && ix0 < WW)) wx0 = 0.0f;
    if (!(ix1 >= 0 && ix1 < WW)) wx1 = 0.0f;
    int cy0 = min(max(iy0, 0), HH - 1), cy1 = min(max(iy1, 0), HH - 1);
    int cx0 = min(max(ix0, 0), WW - 1), cx1 = min(max(ix1, 0), WW - 1);
    wt00[k] = wy0 * wx0; wt01[k] = wy0 * wx1;
    wt10[k] = wy1 * wx0; wt11[k] = wy1 * wx1;
    base00[k] = cy0 * WW + cx0; base01[k] = cy0 * WW + cx1;
    base10[k] = cy1 * WW + cx0; base11[k] = cy1 * WW + cx1;
  }

  int n16 = lane & 15;
  int q = lane >> 4;
  int mrow = cg * 16 + n16;
  f32x4 acc[4] = {f32x4{0,0,0,0}, f32x4{0,0,0,0}, f32x4{0,0,0,0}, f32x4{0,0,0,0}};

#pragma unroll 1
  for (int hf = 0; hf < 2; ++hf) {
    if (hf) __syncthreads();   // previous half's MFMA reads done before overwrite

    // ---- gather channels [16cg+8hf, +8) ----
    const float* xb = x + (b * CC + cg * 16 + 8 * hf) * HWSZ;
#pragma unroll 1
    for (int c16 = 0; c16 < 8; c16 += 2) {
      const float* xp0 = xb + c16 * HWSZ;
      const float* xp1 = xp0 + HWSZ;
      float s2[18];
#pragma unroll
      for (int t = 0; t < 9; ++t) {
        s2[t] = wt00[t] * xp0[base00[t]] + wt01[t] * xp0[base01[t]]
              + wt10[t] * xp0[base10[t]] + wt11[t] * xp0[base11[t]];
        s2[9 + t] = wt00[t] * xp1[base00[t]] + wt01[t] * xp1[base01[t]]
                  + wt10[t] * xp1[base10[t]] + wt11[t] * xp1[base11[t]];
      }
      int k2base = cg * 36 + (c16 * 9) / 2;
#pragma unroll
      for (int j = 0; j < 9; ++j) {
        unsigned pk = bf16rne(s2[2 * j]) | (bf16rne(s2[2 * j + 1]) << 16);
        A_lds[(k2base + j) * 64 + lane] = (int)pk;
      }
    }
    __syncthreads();

    // ---- MFMA over this half's 144 K-pairs ----
#pragma unroll 1
    for (int kk = 0; kk < 9; ++kk) {
      int abase = (kk * 16 + q * 4) * 64 + mrow;
      int4v av;
      av.x = A_lds[abase];
      av.y = A_lds[abase + 64];
      av.z = A_lds[abase + 128];
      av.w = A_lds[abase + 192];
      short8 af = __builtin_bit_cast(short8, av);
      const int* bp = Bg + (hf * 144 + kk * 16 + q * 4) * 64 + n16;
#pragma unroll
      for (int nt = 0; nt < 4; ++nt) {
        int4v bv;
        bv.x = bp[nt * 16];
        bv.y = bp[nt * 16 + 64];
        bv.z = bp[nt * 16 + 128];
        bv.w = bp[nt * 16 + 192];
        short8 bfr = __builtin_bit_cast(short8, bv);
        acc[nt] = __builtin_amdgcn_mfma_f32_16x16x32_bf16(af, bfr, acc[nt], 0, 0, 0);
      }
    }
  }

  // ---- epilogue: D[row=q*4+r][col=n16], px = hw0 + cg*16 + q*4 + r ----
#pragma unroll
  for (int nt = 0; nt < 4; ++nt) {
    int o = nt * 16 + n16;
    float bv = dc_b[o];
    float* yb = ybuf + (size_t)(b * OO + o) * HWSZ + hw0 + cg * 16 + q * 4;
#pragma unroll
    for (int r = 0; r < 4; ++r) yb[r] = acc[nt][r] + bv;
  }
}

__global__ __launch_bounds__(256) void stats_kernel(
    const float* __restrict__ ybuf, float* __restrict__ sums,
    float* __restrict__ sumsq) {
  int o = blockIdx.x & 63;
  int b = blockIdx.x >> 6;
  const float4* yp = (const float4*)(ybuf + (size_t)(b * OO + o) * HWSZ);
  float s = 0.0f, ss = 0.0f;
  for (int i = threadIdx.x; i < HWSZ / 4; i += 256) {
    float4 v = yp[i];
    s += v.x + v.y + v.z + v.w;
    ss += v.x * v.x + v.y * v.y + v.z * v.z + v.w * v.w;
  }
#pragma unroll
  for (int off = 32; off > 0; off >>= 1) {
    s += __shfl_down(s, off);
    ss += __shfl_down(ss, off);
  }
  __shared__ float ls[4], lss[4];
  int wid = threadIdx.x >> 6;
  int lane = threadIdx.x & 63;
  if (lane == 0) { ls[wid] = s; lss[wid] = ss; }
  __syncthreads();
  if (threadIdx.x == 0) {
    float ts = 0.0f, tss = 0.0f;
#pragma unroll
    for (int wv = 0; wv < 4; ++wv) { ts += ls[wv]; tss += lss[wv]; }
    atomicAdd(&sums[o], ts);
    atomicAdd(&sumsq[o], tss);
  }
}

__global__ __launch_bounds__(256) void norm_kernel(
    const float* __restrict__ ybuf, const float* __restrict__ sums,
    const float* __restrict__ sumsq, const float* __restrict__ gamma,
    const float* __restrict__ beta, float* __restrict__ out) {
  int gid = blockIdx.x * 256 + threadIdx.x;   // float4 index
  int flat = gid << 2;
  int o = (flat >> 14) & 63;
  const float invN = 1.0f / (float)(BB * HWSZ);
  float mean = sums[o] * invN;
  float var = sumsq[o] * invN - mean * mean;
  float rstd = rsqrtf(var + 1e-5f);
  float g = gamma[o] * rstd;
  float bta = beta[o] - mean * g;
  float4 v = ((const float4*)ybuf)[gid];
  float4 r;
  r.x = fmaxf(v.x * g + bta, 0.0f);
  r.y = fmaxf(v.y * g + bta, 0.0f);
  r.z = fmaxf(v.z * g + bta, 0.0f);
  r.w = fmaxf(v.w * g + bta, 0.0f);
  ((float4*)out)[gid] = r;
}

extern "C" void kernel_launch(void* const* d_in, const int* in_sizes, int n_in,
                              void* d_out, int out_size, void* d_ws, size_t ws_size,
                              hipStream_t stream) {
  const float* x     = (const float*)d_in[0];
  const float* off_w = (const float*)d_in[1];
  const float* off_b = (const float*)d_in[2];
  const float* dc_w  = (const float*)d_in[3];
  const float* dc_b  = (const float*)d_in[4];
  const float* gamma = (const float*)d_in[5];
  const float* beta  = (const float*)d_in[6];
  float* ws = (float*)d_ws;
  int*   Bg     = (int*)(ws + WS_BG);
  int*   Bgo    = (int*)(ws + WS_BGOFF);
  float* sums   = ws + WS_SUMS;
  float* sumsq  = ws + WS_SUMSQ;
  float* offbuf = ws + WS_OFFBUF;
  float* ybuf   = ws + WS_YBUF;
  float* out = (float*)d_out;

  hipMemsetAsync(sums, 0, 128 * sizeof(float), stream);  // sums + sumsq
  prep_w_kernel<<<64, 256, 0, stream>>>(off_w, dc_w, Bg, Bgo);
  offset_mfma_kernel<<<BB * HWSZ / 64, 256, 0, stream>>>(x, Bgo, off_b, offbuf);
  deform_mfma_kernel<<<BB * HWSZ / 64, 256, 0, stream>>>(x, offbuf, Bg, dc_b, ybuf);
  stats_kernel<<<BB * OO, 256, 0, stream>>>(ybuf, sums, sumsq);
  norm_kernel<<<BB * OO * HWSZ / (4 * 256), 256, 0, stream>>>(ybuf, sums, sumsq, gamma, beta, out);
}

// Round 5
// 198.866 us; speedup vs baseline: 1.6564x; 1.6564x over previous
//
#include <hip/hip_runtime.h>

#define HH 128
#define WW 128
#define HWSZ (HH * WW)
#define CC 64
#define OO 64
#define BB 4
#define NOFF 18
#define KK 576          // C*9
#define K2 288          // KK/2 (bf16 pairs)

// ws layout (dword offsets)
#define WS_BG     0                         // 288*64 = 18432 (deform weights, k=t*64+c pairs)
#define WS_BGO    18432                     // 288*32 = 9216  (offset weights, same K order, N=32 padded)
#define WS_SUMS   47232                     // 64
#define WS_SUMSQ  47296                     // 64
#define WS_OFFBUF 47360                     // 4*18*16384 = 1179648
#define WS_YBUF   1227008                   // 4*64*16384 = 4194304

typedef __attribute__((ext_vector_type(8))) short short8;
typedef __attribute__((ext_vector_type(4))) int int4v;
typedef __attribute__((ext_vector_type(4))) float f32x4;

__device__ inline unsigned bf16rne(float f) {
  unsigned u = __float_as_uint(f);
  u += 0x7fff + ((u >> 16) & 1);
  return u >> 16;
}

// K ordering for BOTH GEMMs: k = t*64 + c (tap-major). Pair p2 = t*32 + j packs
// channels (2j, 2j+1) of tap t. Bg: [288][64], Bgo: [288][32] (o>=18 zero).
__global__ __launch_bounds__(256) void prep_w_kernel(
    const float* __restrict__ off_w, const float* __restrict__ dc_w,
    int* __restrict__ Bg, int* __restrict__ Bgo) {
  int tid = blockIdx.x * 256 + threadIdx.x;
  int stride = gridDim.x * 256;
  for (int i = tid; i < K2 * OO; i += stride) {
    int p2 = i >> 6, o = i & 63;
    int t = p2 >> 5, j = p2 & 31;
    int f0 = (2 * j) * 9 + t;                 // c*9 + t
    unsigned lo = bf16rne(dc_w[o * KK + f0]);
    unsigned hi = bf16rne(dc_w[o * KK + f0 + 9]);
    Bg[i] = (int)(lo | (hi << 16));
  }
  for (int i = tid; i < K2 * 32; i += stride) {
    int p2 = i >> 5, o = i & 31;
    int t = p2 >> 5, j = p2 & 31;
    unsigned pk = 0;
    if (o < NOFF) {
      int f0 = (2 * j) * 9 + t;
      unsigned lo = bf16rne(off_w[o * KK + f0]);
      unsigned hi = bf16rne(off_w[o * KK + f0 + 9]);
      pk = lo | (hi << 16);
    }
    Bgo[i] = (int)pk;
  }
}

// NCHW -> NHWC transpose of x into xT (= d_out scratch, dead until norm).
__global__ __launch_bounds__(256) void nhwc_kernel(
    const float* __restrict__ x, float* __restrict__ xT) {
  __shared__ float T[CC][WW + 1];   // 33 KB, +1 pad
  int b = blockIdx.x >> 7, h = blockIdx.x & 127;
  int tw = threadIdx.x & 127, th = threadIdx.x >> 7;
  const float* xp = x + (size_t)b * CC * HWSZ + h * WW;
#pragma unroll 8
  for (int i = 0; i < 32; ++i) {
    int c = i * 2 + th;
    T[c][tw] = xp[c * HWSZ + tw];
  }
  __syncthreads();
  int tc = threadIdx.x & 63, tq = threadIdx.x >> 6;
  float* op = xT + ((size_t)b * HH + h) * WW * CC;
#pragma unroll 8
  for (int i = 0; i < 32; ++i) {
    int w = i * 4 + tq;
    op[w * CC + tc] = T[tc][w];
  }
}

// Offset conv, barrier-free per-wave skeleton.
// Wave cg owns px range [16cg,16cg+16). Chunk = 3 taps (one ky row).
// Gather lanes = (c4, px): 4 channels x 16 px per load (coalesced segments).
// A region per wave: [16 px][100 dwords] (96 used = 3 taps * 32 pairs).
__global__ __launch_bounds__(256) void offset_mfma_kernel(
    const float* __restrict__ x, const int* __restrict__ Bgo,
    const float* __restrict__ off_b, float* __restrict__ offbuf) {
  __shared__ __align__(16) int A[4 * 16 * 100];   // 25.6 KB

  int cg = threadIdx.x >> 6, lane = threadIdx.x & 63;
  int b = blockIdx.x >> 8, rem = blockIdx.x & 255;
  int h = rem >> 1, w0 = (rem & 1) * 64;
  int hw0 = h * WW + w0;
  int px = lane & 15, c4 = lane >> 4;
  int wcol = w0 + cg * 16 + px;
  const float* xb = x + (size_t)b * CC * HWSZ;
  int arow = (cg * 16 + px) * 100;
  int n16 = lane & 15, q = lane >> 4;
  f32x4 acc[2] = {f32x4{0, 0, 0, 0}, f32x4{0, 0, 0, 0}};

#pragma unroll 1
  for (int chunk = 0; chunk < 3; ++chunk) {
    int cy = h + chunk - 1;
    bool vy = (cy >= 0) && (cy < HH);
    int cys = min(max(cy, 0), HH - 1);
#pragma unroll
    for (int tl = 0; tl < 3; ++tl) {
      int cx = wcol + tl - 1;
      bool v = vy && (cx >= 0) && (cx < WW);
      int cxs = min(max(cx, 0), WW - 1);
      const float* xr = xb + cys * WW + cxs;
#pragma unroll 4
      for (int ci = 0; ci < 16; ++ci) {
        int c = ci * 4 + c4;
        float val = xr[c * HWSZ];
        val = v ? val : 0.0f;
        float part = __shfl_xor(val, 16);
        if ((c4 & 1) == 0) {
          unsigned pk = bf16rne(val) | (bf16rne(part) << 16);
          A[arow + tl * 32 + ci * 2 + (c4 >> 1)] = (int)pk;
        }
      }
    }
    // 6 k-steps over this chunk's 96 pairs
#pragma unroll 1
    for (int kk = 0; kk < 6; ++kk) {
      int4v av = *(const int4v*)&A[(cg * 16 + n16) * 100 + kk * 16 + q * 4];
      short8 af = __builtin_bit_cast(short8, av);
      const int* bp = Bgo + (chunk * 96 + kk * 16 + q * 4) * 32 + n16;
#pragma unroll
      for (int nt = 0; nt < 2; ++nt) {
        int4v bv;
        bv.x = bp[nt * 16];
        bv.y = bp[nt * 16 + 32];
        bv.z = bp[nt * 16 + 64];
        bv.w = bp[nt * 16 + 96];
        short8 bfr = __builtin_bit_cast(short8, bv);
        acc[nt] = __builtin_amdgcn_mfma_f32_16x16x32_bf16(af, bfr, acc[nt], 0, 0, 0);
      }
    }
  }

#pragma unroll
  for (int nt = 0; nt < 2; ++nt) {
    int o = nt * 16 + n16;
    if (o < NOFF) {
      float bv = off_b[o];
      f32x4 r;
#pragma unroll
      for (int r0 = 0; r0 < 4; ++r0) r[r0] = acc[nt][r0] + bv;
      *(f32x4*)(offbuf + (size_t)(b * NOFF + o) * HWSZ + hw0 + cg * 16 + q * 4) = r;
    }
  }
}

// Deform conv, barrier-free per-wave skeleton with NHWC gather.
// Meta (packed coords + bf16 weights) computed once per (px,tap) into LDS.
// Gather: lane = channel, one coalesced 256B load per (px,tap,corner).
__global__ __launch_bounds__(256) void deform_mfma_kernel(
    const float* __restrict__ xT, const float* __restrict__ offbuf,
    const int* __restrict__ Bg, const float* __restrict__ dc_b,
    float* __restrict__ ybuf) {
  __shared__ __align__(16) int A[4 * 16 * 100];   // 25.6 KB
  __shared__ __align__(16) int M[4 * 144 * 4];    // 9.2 KB meta

  int cg = threadIdx.x >> 6, lane = threadIdx.x & 63;
  int b = blockIdx.x >> 8, rem = blockIdx.x & 255;
  int h = rem >> 1, w0 = (rem & 1) * 64;
  int hw0 = h * WW + w0;
  int p0 = cg * 16;

  // ---- meta phase: 144 = 16 px x 9 taps per wave ----
  const float* ob = offbuf + (size_t)b * NOFF * HWSZ;
  int* Mw = M + cg * 144 * 4;
#pragma unroll
  for (int it = 0; it < 3; ++it) {
    int m = it * 64 + lane;
    if (m < 144) {
      int pxl = (unsigned)m / 9u;
      int t = m - pxl * 9;
      int hw = hw0 + p0 + pxl;
      float dy = ob[(2 * t) * HWSZ + hw];
      float dx = ob[(2 * t + 1) * HWSZ + hw];
      float py = (float)(h + t / 3 - 1) + dy;
      float pxf = (float)(w0 + p0 + pxl + (t % 3) - 1) + dx;
      float fy0 = floorf(py), fx0 = floorf(pxf);
      float ay = py - fy0, ax = pxf - fx0;
      int iy0 = (int)fy0, ix0 = (int)fx0;
      int iy1 = iy0 + 1, ix1 = ix0 + 1;
      float wy0 = 1.0f - ay, wy1 = ay, wx0 = 1.0f - ax, wx1 = ax;
      if (!(iy0 >= 0 && iy0 < HH)) wy0 = 0.0f;
      if (!(iy1 >= 0 && iy1 < HH)) wy1 = 0.0f;
      if (!(ix0 >= 0 && ix0 < WW)) wx0 = 0.0f;
      if (!(ix1 >= 0 && ix1 < WW)) wx1 = 0.0f;
      int cy0 = min(max(iy0, 0), HH - 1), cy1 = min(max(iy1, 0), HH - 1);
      int cx0 = min(max(ix0, 0), WW - 1), cx1 = min(max(ix1, 0), WW - 1);
      int4v mv;
      mv.x = cy0 | (cx0 << 8) | (cy1 << 16) | (cx1 << 24);
      mv.y = (int)(bf16rne(wy0 * wx0) | (bf16rne(wy0 * wx1) << 16));
      mv.z = (int)(bf16rne(wy1 * wx0) | (bf16rne(wy1 * wx1) << 16));
      mv.w = 0;
      *(int4v*)&Mw[m * 4] = mv;
    }
  }
  // DS ops are in-order per wave; meta/A regions are wave-private -> no barrier.

  int n16 = lane & 15, q = lane >> 4;
  const float* xTb = xT + (size_t)b * HWSZ * CC;
  unsigned short* A16 = (unsigned short*)A;
  f32x4 acc[4] = {f32x4{0,0,0,0}, f32x4{0,0,0,0}, f32x4{0,0,0,0}, f32x4{0,0,0,0}};

#pragma unroll 1
  for (int chunk = 0; chunk < 3; ++chunk) {
#pragma unroll 1
    for (int tl = 0; tl < 3; ++tl) {
#pragma unroll 4
      for (int pxl = 0; pxl < 16; ++pxl) {
        int4v mv = *(const int4v*)&Mw[(pxl * 9 + chunk * 3 + tl) * 4];
        int m0 = mv.x;
        int cy0 = m0 & 255, cx0 = (m0 >> 8) & 255;
        int cy1 = (m0 >> 16) & 255, cx1 = (m0 >> 24) & 255;
        float v00 = xTb[(cy0 * WW + cx0) * CC + lane];
        float v01 = xTb[(cy0 * WW + cx1) * CC + lane];
        float v10 = xTb[(cy1 * WW + cx0) * CC + lane];
        float v11 = xTb[(cy1 * WW + cx1) * CC + lane];
        float w00 = __uint_as_float(((unsigned)mv.y) << 16);
        float w01 = __uint_as_float(((unsigned)mv.y) & 0xffff0000u);
        float w10 = __uint_as_float(((unsigned)mv.z) << 16);
        float w11 = __uint_as_float(((unsigned)mv.z) & 0xffff0000u);
        float s = w00 * v00;
        s = fmaf(w01, v01, s);
        s = fmaf(w10, v10, s);
        s = fmaf(w11, v11, s);
        A16[(cg * 16 + pxl) * 200 + tl * 64 + lane] = (unsigned short)bf16rne(s);
      }
    }
    // 6 k-steps over this chunk's 96 pairs (k = t*64+c order)
#pragma unroll 1
    for (int kk = 0; kk < 6; ++kk) {
      int4v av = *(const int4v*)&A[(cg * 16 + n16) * 100 + kk * 16 + q * 4];
      short8 af = __builtin_bit_cast(short8, av);
      const int* bp = Bg + (chunk * 96 + kk * 16 + q * 4) * 64 + n16;
#pragma unroll
      for (int nt = 0; nt < 4; ++nt) {
        int4v bv;
        bv.x = bp[nt * 16];
        bv.y = bp[nt * 16 + 64];
        bv.z = bp[nt * 16 + 128];
        bv.w = bp[nt * 16 + 192];
        short8 bfr = __builtin_bit_cast(short8, bv);
        acc[nt] = __builtin_amdgcn_mfma_f32_16x16x32_bf16(af, bfr, acc[nt], 0, 0, 0);
      }
    }
  }

  // ---- epilogue: D[row=q*4+r][col=n16]; px = hw0 + cg*16 + q*4 + r ----
#pragma unroll
  for (int nt = 0; nt < 4; ++nt) {
    int o = nt * 16 + n16;
    float bv = dc_b[o];
    f32x4 r;
#pragma unroll
    for (int r0 = 0; r0 < 4; ++r0) r[r0] = acc[nt][r0] + bv;
    *(f32x4*)(ybuf + (size_t)(b * OO + o) * HWSZ + hw0 + cg * 16 + q * 4) = r;
  }
}

__global__ __launch_bounds__(256) void stats_kernel(
    const float* __restrict__ ybuf, float* __restrict__ sums,
    float* __restrict__ sumsq) {
  int o = blockIdx.x & 63;
  int b = blockIdx.x >> 6;
  const float4* yp = (const float4*)(ybuf + (size_t)(b * OO + o) * HWSZ);
  float s = 0.0f, ss = 0.0f;
  for (int i = threadIdx.x; i < HWSZ / 4; i += 256) {
    float4 v = yp[i];
    s += v.x + v.y + v.z + v.w;
    ss += v.x * v.x + v.y * v.y + v.z * v.z + v.w * v.w;
  }
#pragma unroll
  for (int off = 32; off > 0; off >>= 1) {
    s += __shfl_down(s, off);
    ss += __shfl_down(ss, off);
  }
  __shared__ float ls[4], lss[4];
  int wid = threadIdx.x >> 6;
  int lane = threadIdx.x & 63;
  if (lane == 0) { ls[wid] = s; lss[wid] = ss; }
  __syncthreads();
  if (threadIdx.x == 0) {
    float ts = 0.0f, tss = 0.0f;
#pragma unroll
    for (int wv = 0; wv < 4; ++wv) { ts += ls[wv]; tss += lss[wv]; }
    atomicAdd(&sums[o], ts);
    atomicAdd(&sumsq[o], tss);
  }
}

__global__ __launch_bounds__(256) void norm_kernel(
    const float* __restrict__ ybuf, const float* __restrict__ sums,
    const float* __restrict__ sumsq, const float* __restrict__ gamma,
    const float* __restrict__ beta, float* __restrict__ out) {
  int gid = blockIdx.x * 256 + threadIdx.x;
  int flat = gid << 2;
  int o = (flat >> 14) & 63;
  const float invN = 1.0f / (float)(BB * HWSZ);
  float mean = sums[o] * invN;
  float var = sumsq[o] * invN - mean * mean;
  float rstd = rsqrtf(var + 1e-5f);
  float g = gamma[o] * rstd;
  float bta = beta[o] - mean * g;
  float4 v = ((const float4*)ybuf)[gid];
  float4 r;
  r.x = fmaxf(v.x * g + bta, 0.0f);
  r.y = fmaxf(v.y * g + bta, 0.0f);
  r.z = fmaxf(v.z * g + bta, 0.0f);
  r.w = fmaxf(v.w * g + bta, 0.0f);
  ((float4*)out)[gid] = r;
}

extern "C" void kernel_launch(void* const* d_in, const int* in_sizes, int n_in,
                              void* d_out, int out_size, void* d_ws, size_t ws_size,
                              hipStream_t stream) {
  const float* x     = (const float*)d_in[0];
  const float* off_w = (const float*)d_in[1];
  const float* off_b = (const float*)d_in[2];
  const float* dc_w  = (const float*)d_in[3];
  const float* dc_b  = (const float*)d_in[4];
  const float* gamma = (const float*)d_in[5];
  const float* beta  = (const float*)d_in[6];
  float* ws = (float*)d_ws;
  int*   Bg     = (int*)(ws + WS_BG);
  int*   Bgo    = (int*)(ws + WS_BGO);
  float* sums   = ws + WS_SUMS;
  float* sumsq  = ws + WS_SUMSQ;
  float* offbuf = ws + WS_OFFBUF;
  float* ybuf   = ws + WS_YBUF;
  float* out = (float*)d_out;
  float* xT  = (float*)d_out;   // d_out (16MB) doubles as NHWC scratch; dead until norm

  hipMemsetAsync(sums, 0, 128 * sizeof(float), stream);
  prep_w_kernel<<<64, 256, 0, stream>>>(off_w, dc_w, Bg, Bgo);
  nhwc_kernel<<<BB * HH, 256, 0, stream>>>(x, xT);
  offset_mfma_kernel<<<BB * HWSZ / 64, 256, 0, stream>>>(x, Bgo, off_b, offbuf);
  deform_mfma_kernel<<<BB * HWSZ / 64, 256, 0, stream>>>(xT, offbuf, Bg, dc_b, ybuf);
  stats_kernel<<<BB * OO, 256, 0, stream>>>(ybuf, sums, sumsq);
  norm_kernel<<<BB * OO * HWSZ / (4 * 256), 256, 0, stream>>>(ybuf, sums, sumsq, gamma, beta, out);
}

// Round 6
// 160.429 us; speedup vs baseline: 2.0532x; 1.2396x over previous
//
#include <hip/hip_runtime.h>

#define HH 128
#define WW 128
#define HWSZ (HH * WW)
#define CC 64
#define OO 64
#define BB 4
#define NOFF 18
#define KK 576          // C*9
#define K2 288          // KK/2 (bf16 pairs)

// ws layout (dword offsets)
#define WS_BG     0                         // 72*64*4 = 18432 (deform weights, quad-packed)
#define WS_BGO    18432                     // 72*32*4 = 9216  (offset weights, quad-packed, N=32)
#define WS_SUMS   47232                     // 64
#define WS_SUMSQ  47296                     // 64
#define WS_OFFBUF 47360                     // 4*18*16384 = 1179648
#define WS_YBUF   1227008                   // 4*64*16384 = 4194304

typedef __attribute__((ext_vector_type(8))) short short8;
typedef __attribute__((ext_vector_type(4))) int int4v;
typedef __attribute__((ext_vector_type(4))) float f32x4;

__device__ inline unsigned bf16rne(float f) {
  unsigned u = __float_as_uint(f);
  u += 0x7fff + ((u >> 16) & 1);
  return u >> 16;
}
__device__ inline float us2f(unsigned short v) {
  return __uint_as_float(((unsigned)v) << 16);
}

// K order: k = t*64 + c (tap-major). Pair k2 = t*32 + jj packs channels (2jj,2jj+1).
// Quad-packed B: for k-quad g (k2 = g*4+j), col o: the 4 dwords j=0..3 contiguous.
//   Bg[(g*64 + o)*4 + j]   (deform, o<64)
//   Bgo[(g*32 + o)*4 + j]  (offset, o<32, o>=18 zero)
__global__ __launch_bounds__(256) void prep_w_kernel(
    const float* __restrict__ off_w, const float* __restrict__ dc_w,
    int* __restrict__ Bg, int* __restrict__ Bgo) {
  int tid = blockIdx.x * 256 + threadIdx.x;
  int stride = gridDim.x * 256;
  for (int i = tid; i < 72 * 64 * 4; i += stride) {
    int j = i & 3, o = (i >> 2) & 63, g = i >> 8;
    int k2 = g * 4 + j, t = k2 >> 5, jj = k2 & 31;
    unsigned lo = bf16rne(dc_w[o * KK + (2 * jj) * 9 + t]);
    unsigned hi = bf16rne(dc_w[o * KK + (2 * jj + 1) * 9 + t]);
    Bg[i] = (int)(lo | (hi << 16));
  }
  for (int i = tid; i < 72 * 32 * 4; i += stride) {
    int j = i & 3, o = (i >> 2) & 31, g = i >> 7;
    int k2 = g * 4 + j, t = k2 >> 5, jj = k2 & 31;
    unsigned pk = 0;
    if (o < NOFF) {
      unsigned lo = bf16rne(off_w[o * KK + (2 * jj) * 9 + t]);
      unsigned hi = bf16rne(off_w[o * KK + (2 * jj + 1) * 9 + t]);
      pk = lo | (hi << 16);
    }
    Bgo[i] = (int)pk;
  }
}

// NCHW fp32 -> NHWC bf16 (channel pairs packed in dwords). xTu: [b][h][w][32 dwords]
__global__ __launch_bounds__(256) void nhwc_kernel(
    const float* __restrict__ x, unsigned int* __restrict__ xTu) {
  __shared__ float T[CC][WW + 1];
  int b = blockIdx.x >> 7, h = blockIdx.x & 127;
  int tw = threadIdx.x & 127, th = threadIdx.x >> 7;
  const float* xp = x + (size_t)b * CC * HWSZ + h * WW;
#pragma unroll 8
  for (int i = 0; i < 32; ++i) {
    int c = i * 2 + th;
    T[c][tw] = xp[c * HWSZ + tw];
  }
  __syncthreads();
  int c2 = threadIdx.x & 31, wq = threadIdx.x >> 5;
  unsigned int* op = xTu + ((size_t)(b * HH + h) * WW) * 32;
#pragma unroll 8
  for (int i = 0; i < 16; ++i) {
    int w = i * 8 + wq;
    unsigned pk = bf16rne(T[2 * c2][w]) | (bf16rne(T[2 * c2 + 1][w]) << 16);
    op[w * 32 + c2] = pk;
  }
}

// Offset conv: im2col is now a pure copy from NHWC-bf16 xT (k = t*64+c order).
// Wave cg owns px [16cg,16cg+16). Per tap: 2 dwordx4 loads cover 16px x 8ch/lane.
__global__ __launch_bounds__(256) void offset_mfma_kernel(
    const unsigned int* __restrict__ xTu, const int* __restrict__ Bgo,
    const float* __restrict__ off_b, float* __restrict__ offbuf) {
  __shared__ __align__(16) int A[4 * 16 * 100];   // 25.6 KB

  int cg = threadIdx.x >> 6, lane = threadIdx.x & 63;
  int b = blockIdx.x >> 8, rem = blockIdx.x & 255;
  int h = rem >> 1, w0 = (rem & 1) * 64;
  int hw0 = h * WW + w0;
  int pg = lane >> 3, part = lane & 7;
  int n16 = lane & 15, q = lane >> 4;
  const unsigned int* xb = xTu + (size_t)b * HWSZ * 32;
  f32x4 acc[2] = {f32x4{0, 0, 0, 0}, f32x4{0, 0, 0, 0}};

#pragma unroll 1
  for (int chunk = 0; chunk < 3; ++chunk) {
    int cy = h + chunk - 1;
    bool vy = (cy >= 0) && (cy < HH);
    int cys = min(max(cy, 0), HH - 1);
#pragma unroll
    for (int tl = 0; tl < 3; ++tl) {
#pragma unroll
      for (int i = 0; i < 2; ++i) {
        int px = i * 8 + pg;
        int cx = w0 + cg * 16 + px + tl - 1;
        bool v = vy && (cx >= 0) && (cx < WW);
        int cxs = min(max(cx, 0), WW - 1);
        int4v val = *(const int4v*)&xb[(cys * WW + cxs) * 32 + part * 4];
        if (!v) { val.x = 0; val.y = 0; val.z = 0; val.w = 0; }
        *(int4v*)&A[(cg * 16 + px) * 100 + tl * 32 + part * 4] = val;
      }
    }
#pragma unroll 1
    for (int kk = 0; kk < 6; ++kk) {
      int4v av = *(const int4v*)&A[(cg * 16 + n16) * 100 + kk * 16 + q * 4];
      short8 af = __builtin_bit_cast(short8, av);
      int g = chunk * 24 + kk * 4 + q;
#pragma unroll
      for (int nt = 0; nt < 2; ++nt) {
        int4v bv = *(const int4v*)&Bgo[(g * 32 + nt * 16 + n16) * 4];
        short8 bfr = __builtin_bit_cast(short8, bv);
        acc[nt] = __builtin_amdgcn_mfma_f32_16x16x32_bf16(af, bfr, acc[nt], 0, 0, 0);
      }
    }
  }

#pragma unroll
  for (int nt = 0; nt < 2; ++nt) {
    int o = nt * 16 + n16;
    if (o < NOFF) {
      float bv = off_b[o];
      f32x4 r;
#pragma unroll
      for (int r0 = 0; r0 < 4; ++r0) r[r0] = acc[nt][r0] + bv;
      *(f32x4*)(offbuf + (size_t)(b * NOFF + o) * HWSZ + hw0 + cg * 16 + q * 4) = r;
    }
  }
}

// Deform conv: NHWC-bf16 gather + MFMA + fused BN-stats reduction.
__global__ __launch_bounds__(256) void deform_mfma_kernel(
    const unsigned short* __restrict__ xTs, const float* __restrict__ offbuf,
    const int* __restrict__ Bg, const float* __restrict__ dc_b,
    float* __restrict__ ybuf, float* __restrict__ sums, float* __restrict__ sumsq) {
  __shared__ __align__(16) int A[4 * 16 * 100];   // 25.6 KB
  __shared__ __align__(16) int M[4 * 144 * 4];    // 9.2 KB meta
  __shared__ float Ssum[256], Ssq[256];           // 2 KB

  int cg = threadIdx.x >> 6, lane = threadIdx.x & 63;
  int b = blockIdx.x >> 8, rem = blockIdx.x & 255;
  int h = rem >> 1, w0 = (rem & 1) * 64;
  int hw0 = h * WW + w0;
  int p0 = cg * 16;

  // ---- meta: 144 = 16 px x 9 taps per wave; pack 4 linear offsets + 4 bf16 wts ----
  const float* ob = offbuf + (size_t)b * NOFF * HWSZ;
  int* Mw = M + cg * 144 * 4;
#pragma unroll
  for (int it = 0; it < 3; ++it) {
    int m = it * 64 + lane;
    if (m < 144) {
      int pxl = (unsigned)m / 9u;
      int t = m - pxl * 9;
      int hw = hw0 + p0 + pxl;
      float dy = ob[(2 * t) * HWSZ + hw];
      float dx = ob[(2 * t + 1) * HWSZ + hw];
      float py = (float)(h + t / 3 - 1) + dy;
      float pxf = (float)(w0 + p0 + pxl + (t % 3) - 1) + dx;
      float fy0 = floorf(py), fx0 = floorf(pxf);
      float ay = py - fy0, ax = pxf - fx0;
      int iy0 = (int)fy0, ix0 = (int)fx0;
      int iy1 = iy0 + 1, ix1 = ix0 + 1;
      float wy0 = 1.0f - ay, wy1 = ay, wx0 = 1.0f - ax, wx1 = ax;
      if (!(iy0 >= 0 && iy0 < HH)) wy0 = 0.0f;
      if (!(iy1 >= 0 && iy1 < HH)) wy1 = 0.0f;
      if (!(ix0 >= 0 && ix0 < WW)) wx0 = 0.0f;
      if (!(ix1 >= 0 && ix1 < WW)) wx1 = 0.0f;
      int cy0 = min(max(iy0, 0), HH - 1), cy1 = min(max(iy1, 0), HH - 1);
      int cx0 = min(max(ix0, 0), WW - 1), cx1 = min(max(ix1, 0), WW - 1);
      int4v mv;
      mv.x = (cy0 * WW + cx0) | ((cy0 * WW + cx1) << 16);
      mv.y = (cy1 * WW + cx0) | ((cy1 * WW + cx1) << 16);
      mv.z = (int)(bf16rne(wy0 * wx0) | (bf16rne(wy0 * wx1) << 16));
      mv.w = (int)(bf16rne(wy1 * wx0) | (bf16rne(wy1 * wx1) << 16));
      *(int4v*)&Mw[m * 4] = mv;
    }
  }

  int n16 = lane & 15, q = lane >> 4;
  const unsigned short* xb = xTs + (size_t)b * HWSZ * 64;
  unsigned short* A16 = (unsigned short*)A;
  f32x4 acc[4] = {f32x4{0,0,0,0}, f32x4{0,0,0,0}, f32x4{0,0,0,0}, f32x4{0,0,0,0}};

#pragma unroll 1
  for (int chunk = 0; chunk < 3; ++chunk) {
#pragma unroll 1
    for (int tl = 0; tl < 3; ++tl) {
#pragma unroll 4
      for (int pxl = 0; pxl < 16; ++pxl) {
        int4v mv = *(const int4v*)&Mw[(pxl * 9 + chunk * 3 + tl) * 4];
        int o00 = mv.x & 0xffff, o01 = ((unsigned)mv.x) >> 16;
        int o10 = mv.y & 0xffff, o11 = ((unsigned)mv.y) >> 16;
        float f00 = us2f(xb[o00 * 64 + lane]);
        float f01 = us2f(xb[o01 * 64 + lane]);
        float f10 = us2f(xb[o10 * 64 + lane]);
        float f11 = us2f(xb[o11 * 64 + lane]);
        float w00 = __uint_as_float(((unsigned)mv.z) << 16);
        float w01 = __uint_as_float(((unsigned)mv.z) & 0xffff0000u);
        float w10 = __uint_as_float(((unsigned)mv.w) << 16);
        float w11 = __uint_as_float(((unsigned)mv.w) & 0xffff0000u);
        float s = w00 * f00;
        s = fmaf(w01, f01, s);
        s = fmaf(w10, f10, s);
        s = fmaf(w11, f11, s);
        A16[(cg * 16 + pxl) * 200 + tl * 64 + lane] = (unsigned short)bf16rne(s);
      }
    }
#pragma unroll 1
    for (int kk = 0; kk < 6; ++kk) {
      int4v av = *(const int4v*)&A[(cg * 16 + n16) * 100 + kk * 16 + q * 4];
      short8 af = __builtin_bit_cast(short8, av);
      int g = chunk * 24 + kk * 4 + q;
#pragma unroll
      for (int nt = 0; nt < 4; ++nt) {
        int4v bv = *(const int4v*)&Bg[(g * 64 + nt * 16 + n16) * 4];
        short8 bfr = __builtin_bit_cast(short8, bv);
        acc[nt] = __builtin_amdgcn_mfma_f32_16x16x32_bf16(af, bfr, acc[nt], 0, 0, 0);
      }
    }
  }

  // ---- epilogue: store y + per-wave stats reduce ----
#pragma unroll
  for (int nt = 0; nt < 4; ++nt) {
    int o = nt * 16 + n16;
    float bv = dc_b[o];
    f32x4 r;
    float s = 0.0f, ss = 0.0f;
#pragma unroll
    for (int r0 = 0; r0 < 4; ++r0) {
      r[r0] = acc[nt][r0] + bv;
      s += r[r0];
      ss += r[r0] * r[r0];
    }
    *(f32x4*)(ybuf + (size_t)(b * OO + o) * HWSZ + hw0 + cg * 16 + q * 4) = r;
    s += __shfl_xor(s, 16);  s += __shfl_xor(s, 32);
    ss += __shfl_xor(ss, 16); ss += __shfl_xor(ss, 32);
    if (lane < 16) {  // lane == n16
      Ssum[cg * 64 + nt * 16 + lane] = s;
      Ssq[cg * 64 + nt * 16 + lane] = ss;
    }
  }
  __syncthreads();
  if (cg == 0) {
    float ts = Ssum[lane] + Ssum[64 + lane] + Ssum[128 + lane] + Ssum[192 + lane];
    float tq = Ssq[lane] + Ssq[64 + lane] + Ssq[128 + lane] + Ssq[192 + lane];
    atomicAdd(&sums[lane], ts);
    atomicAdd(&sumsq[lane], tq);
  }
}

__global__ __launch_bounds__(256) void norm_kernel(
    const float* __restrict__ ybuf, const float* __restrict__ sums,
    const float* __restrict__ sumsq, const float* __restrict__ gamma,
    const float* __restrict__ beta, float* __restrict__ out) {
  int gid = blockIdx.x * 256 + threadIdx.x;
  int flat = gid << 2;
  int o = (flat >> 14) & 63;
  const float invN = 1.0f / (float)(BB * HWSZ);
  float mean = sums[o] * invN;
  float var = sumsq[o] * invN - mean * mean;
  float rstd = rsqrtf(var + 1e-5f);
  float g = gamma[o] * rstd;
  float bta = beta[o] - mean * g;
  float4 v = ((const float4*)ybuf)[gid];
  float4 r;
  r.x = fmaxf(v.x * g + bta, 0.0f);
  r.y = fmaxf(v.y * g + bta, 0.0f);
  r.z = fmaxf(v.z * g + bta, 0.0f);
  r.w = fmaxf(v.w * g + bta, 0.0f);
  ((float4*)out)[gid] = r;
}

extern "C" void kernel_launch(void* const* d_in, const int* in_sizes, int n_in,
                              void* d_out, int out_size, void* d_ws, size_t ws_size,
                              hipStream_t stream) {
  const float* x     = (const float*)d_in[0];
  const float* off_w = (const float*)d_in[1];
  const float* off_b = (const float*)d_in[2];
  const float* dc_w  = (const float*)d_in[3];
  const float* dc_b  = (const float*)d_in[4];
  const float* gamma = (const float*)d_in[5];
  const float* beta  = (const float*)d_in[6];
  float* ws = (float*)d_ws;
  int*   Bg     = (int*)(ws + WS_BG);
  int*   Bgo    = (int*)(ws + WS_BGO);
  float* sums   = ws + WS_SUMS;
  float* sumsq  = ws + WS_SUMSQ;
  float* offbuf = ws + WS_OFFBUF;
  float* ybuf   = ws + WS_YBUF;
  float* out = (float*)d_out;
  // d_out (16 MB fp32) doubles as NHWC-bf16 scratch (8 MB); dead until norm writes.
  unsigned int*   xTu = (unsigned int*)d_out;
  unsigned short* xTs = (unsigned short*)d_out;

  hipMemsetAsync(sums, 0, 128 * sizeof(float), stream);
  prep_w_kernel<<<64, 256, 0, stream>>>(off_w, dc_w, Bg, Bgo);
  nhwc_kernel<<<BB * HH, 256, 0, stream>>>(x, xTu);
  offset_mfma_kernel<<<BB * HWSZ / 64, 256, 0, stream>>>(xTu, Bgo, off_b, offbuf);
  deform_mfma_kernel<<<BB * HWSZ / 64, 256, 0, stream>>>(xTs, offbuf, Bg, dc_b, ybuf, sums, sumsq);
  norm_kernel<<<BB * OO * HWSZ / (4 * 256), 256, 0, stream>>>(ybuf, sums, sumsq, gamma, beta, out);
}

// Round 7
// 141.779 us; speedup vs baseline: 2.3233x; 1.1315x over previous
//
#include <hip/hip_runtime.h>

#define HH 128
#define WW 128
#define HWSZ (HH * WW)
#define CC 64
#define OO 64
#define BB 4
#define NOFF 18
#define KK 576          // C*9

// ws layout (dword offsets)
#define WS_BG     0                         // 72*64*4 = 18432 (deform weights, quad-packed)
#define WS_BGO    18432                     // 72*32*4 = 9216  (offset weights, quad-packed, N=32)
#define WS_SUMS   27648                     // 64
#define WS_SUMSQ  27712                     // 64
#define WS_YBUF   27776                     // 4*64*16384 = 4194304

typedef __attribute__((ext_vector_type(8))) short short8;
typedef __attribute__((ext_vector_type(4))) int int4v;
typedef __attribute__((ext_vector_type(4))) float f32x4;

__device__ inline unsigned bf16rne(float f) {
  unsigned u = __float_as_uint(f);
  u += 0x7fff + ((u >> 16) & 1);
  return u >> 16;
}

// One kernel: NHWC-bf16 transpose (blocks 0..511) + weight repack + stats zero
// (blocks 512..575).
// K order: k = t*64 + c. Pair k2 = t*32 + jj packs channels (2jj,2jj+1).
// Quad-packed B: k-quad g (k2 = g*4+j): Bg[(g*64+o)*4+j], Bgo[(g*32+o)*4+j].
__global__ __launch_bounds__(256) void prep_kernel(
    const float* __restrict__ x, const float* __restrict__ off_w,
    const float* __restrict__ dc_w, unsigned int* __restrict__ xTu,
    int* __restrict__ Bg, int* __restrict__ Bgo, float* __restrict__ sums) {
  int bid = blockIdx.x;
  if (bid < BB * HH) {
    __shared__ float T[CC][WW + 1];
    int b = bid >> 7, h = bid & 127;
    int tw = threadIdx.x & 127, th = threadIdx.x >> 7;
    const float* xp = x + (size_t)b * CC * HWSZ + h * WW;
#pragma unroll 8
    for (int i = 0; i < 32; ++i) {
      int c = i * 2 + th;
      T[c][tw] = xp[c * HWSZ + tw];
    }
    __syncthreads();
    int c2 = threadIdx.x & 31, wq = threadIdx.x >> 5;
    unsigned int* op = xTu + ((size_t)(b * HH + h) * WW) * 32;
#pragma unroll 8
    for (int i = 0; i < 16; ++i) {
      int w = i * 8 + wq;
      unsigned pk = bf16rne(T[2 * c2][w]) | (bf16rne(T[2 * c2 + 1][w]) << 16);
      op[w * 32 + c2] = pk;
    }
  } else {
    int pb = bid - BB * HH;
    int tid = pb * 256 + threadIdx.x;
    int stride = 64 * 256;
    for (int i = tid; i < 72 * 64 * 4; i += stride) {
      int j = i & 3, o = (i >> 2) & 63, g = i >> 8;
      int k2 = g * 4 + j, t = k2 >> 5, jj = k2 & 31;
      unsigned lo = bf16rne(dc_w[o * KK + (2 * jj) * 9 + t]);
      unsigned hi = bf16rne(dc_w[o * KK + (2 * jj + 1) * 9 + t]);
      Bg[i] = (int)(lo | (hi << 16));
    }
    for (int i = tid; i < 72 * 32 * 4; i += stride) {
      int j = i & 3, o = (i >> 2) & 31, g = i >> 7;
      int k2 = g * 4 + j, t = k2 >> 5, jj = k2 & 31;
      unsigned pk = 0;
      if (o < NOFF) {
        unsigned lo = bf16rne(off_w[o * KK + (2 * jj) * 9 + t]);
        unsigned hi = bf16rne(off_w[o * KK + (2 * jj + 1) * 9 + t]);
        pk = lo | (hi << 16);
      }
      Bgo[i] = (int)pk;
    }
    if (tid < 128) sums[tid] = 0.0f;   // sums + sumsq contiguous
  }
}

// Fused offset-conv + deform-conv + BN-stats. Block = 64 px x 4 waves; wave cg
// owns px tile [16cg,16cg+16) end-to-end. Barrier-free until the final
// cross-wave stats sum (all LDS regions wave-private; DS ops in-order per wave).
__global__ __launch_bounds__(256) void fused_kernel(
    const unsigned int* __restrict__ xTu, const int* __restrict__ Bg,
    const int* __restrict__ Bgo, const float* __restrict__ off_b,
    const float* __restrict__ dc_b, float* __restrict__ ybuf,
    float* __restrict__ sums, float* __restrict__ sumsq) {
  __shared__ __align__(16) int A[4 * 16 * 100];   // 25.6 KB (also stats alias)
  __shared__ __align__(16) int M[4 * 144 * 4];    // 9.2 KB meta
  __shared__ float offL[4][NOFF][16];             // 4.6 KB offsets

  int cg = threadIdx.x >> 6, lane = threadIdx.x & 63;
  int b = blockIdx.x >> 8, rem = blockIdx.x & 255;
  int h = rem >> 1, w0 = (rem & 1) * 64;
  int hw0 = h * WW + w0;
  int p0 = cg * 16;
  int n16 = lane & 15, q = lane >> 4;
  int pg = lane >> 3, part = lane & 7;
  const unsigned int* xbu = xTu + (size_t)b * HWSZ * 32;

  // ---------- phase 1: offset conv (im2col copy + MFMA) ----------
  f32x4 acc2[2] = {f32x4{0, 0, 0, 0}, f32x4{0, 0, 0, 0}};
#pragma unroll 1
  for (int chunk = 0; chunk < 3; ++chunk) {
    int cy = h + chunk - 1;
    bool vy = (cy >= 0) && (cy < HH);
    int cys = min(max(cy, 0), HH - 1);
#pragma unroll
    for (int tl = 0; tl < 3; ++tl) {
#pragma unroll
      for (int i = 0; i < 2; ++i) {
        int px = i * 8 + pg;
        int cx = w0 + p0 + px + tl - 1;
        bool v = vy && (cx >= 0) && (cx < WW);
        int cxs = min(max(cx, 0), WW - 1);
        int4v val = *(const int4v*)&xbu[(cys * WW + cxs) * 32 + part * 4];
        if (!v) { val.x = 0; val.y = 0; val.z = 0; val.w = 0; }
        *(int4v*)&A[(p0 + px) * 100 + tl * 32 + part * 4] = val;
      }
    }
#pragma unroll 1
    for (int kk = 0; kk < 6; ++kk) {
      int4v av = *(const int4v*)&A[(p0 + n16) * 100 + kk * 16 + q * 4];
      short8 af = __builtin_bit_cast(short8, av);
      int g = chunk * 24 + kk * 4 + q;
#pragma unroll
      for (int nt = 0; nt < 2; ++nt) {
        int4v bv = *(const int4v*)&Bgo[(g * 32 + nt * 16 + n16) * 4];
        short8 bfr = __builtin_bit_cast(short8, bv);
        acc2[nt] = __builtin_amdgcn_mfma_f32_16x16x32_bf16(af, bfr, acc2[nt], 0, 0, 0);
      }
    }
  }
#pragma unroll
  for (int nt = 0; nt < 2; ++nt) {
    int o = nt * 16 + n16;
    if (o < NOFF) {
      float bv = off_b[o];
#pragma unroll
      for (int r = 0; r < 4; ++r) offL[cg][o][q * 4 + r] = acc2[nt][r] + bv;
    }
  }

  // ---------- phase 2: bilinear meta (wave-private) ----------
  int* Mw = M + cg * 144 * 4;
#pragma unroll
  for (int it = 0; it < 3; ++it) {
    int m = it * 64 + lane;
    if (m < 144) {
      int pxl = (unsigned)m / 9u;
      int t = m - pxl * 9;
      float dy = offL[cg][2 * t][pxl];
      float dx = offL[cg][2 * t + 1][pxl];
      float py = (float)(h + t / 3 - 1) + dy;
      float pxf = (float)(w0 + p0 + pxl + (t % 3) - 1) + dx;
      float fy0 = floorf(py), fx0 = floorf(pxf);
      float ay = py - fy0, ax = pxf - fx0;
      int iy0 = (int)fy0, ix0 = (int)fx0;
      int iy1 = iy0 + 1, ix1 = ix0 + 1;
      float wy0 = 1.0f - ay, wy1 = ay, wx0 = 1.0f - ax, wx1 = ax;
      if (!(iy0 >= 0 && iy0 < HH)) wy0 = 0.0f;
      if (!(iy1 >= 0 && iy1 < HH)) wy1 = 0.0f;
      if (!(ix0 >= 0 && ix0 < WW)) wx0 = 0.0f;
      if (!(ix1 >= 0 && ix1 < WW)) wx1 = 0.0f;
      int cy0 = min(max(iy0, 0), HH - 1), cy1 = min(max(iy1, 0), HH - 1);
      int cx0 = min(max(ix0, 0), WW - 1), cx1 = min(max(ix1, 0), WW - 1);
      int4v mv;
      mv.x = (cy0 * WW + cx0) | ((cy0 * WW + cx1) << 16);
      mv.y = (cy1 * WW + cx0) | ((cy1 * WW + cx1) << 16);
      mv.z = (int)(bf16rne(wy0 * wx0) | (bf16rne(wy0 * wx1) << 16));
      mv.w = (int)(bf16rne(wy1 * wx0) | (bf16rne(wy1 * wx1) << 16));
      *(int4v*)&Mw[m * 4] = mv;
    }
  }

  // ---------- phase 3: pair-gather + MFMA ----------
  int p = lane >> 5;        // pixel-in-pair
  int c2 = lane & 31;       // channel pair
  f32x4 acc[4] = {f32x4{0,0,0,0}, f32x4{0,0,0,0}, f32x4{0,0,0,0}, f32x4{0,0,0,0}};
#pragma unroll 1
  for (int chunk = 0; chunk < 3; ++chunk) {
#pragma unroll 1
    for (int tl = 0; tl < 3; ++tl) {
#pragma unroll 4
      for (int pp = 0; pp < 16; pp += 2) {
        int pxl = pp + p;
        int4v mv = *(const int4v*)&Mw[(pxl * 9 + chunk * 3 + tl) * 4];
        unsigned o00 = mv.x & 0xffff, o01 = ((unsigned)mv.x) >> 16;
        unsigned o10 = mv.y & 0xffff, o11 = ((unsigned)mv.y) >> 16;
        unsigned d00 = xbu[o00 * 32 + c2];
        unsigned d01 = xbu[o01 * 32 + c2];
        unsigned d10 = xbu[o10 * 32 + c2];
        unsigned d11 = xbu[o11 * 32 + c2];
        float w00 = __uint_as_float(((unsigned)mv.z) << 16);
        float w01 = __uint_as_float(((unsigned)mv.z) & 0xffff0000u);
        float w10 = __uint_as_float(((unsigned)mv.w) << 16);
        float w11 = __uint_as_float(((unsigned)mv.w) & 0xffff0000u);
        float slo = w00 * __uint_as_float(d00 << 16);
        slo = fmaf(w01, __uint_as_float(d01 << 16), slo);
        slo = fmaf(w10, __uint_as_float(d10 << 16), slo);
        slo = fmaf(w11, __uint_as_float(d11 << 16), slo);
        float shi = w00 * __uint_as_float(d00 & 0xffff0000u);
        shi = fmaf(w01, __uint_as_float(d01 & 0xffff0000u), shi);
        shi = fmaf(w10, __uint_as_float(d10 & 0xffff0000u), shi);
        shi = fmaf(w11, __uint_as_float(d11 & 0xffff0000u), shi);
        // pack: round-to-nearest (ties away) both halves, one v_perm
        unsigned pk = __builtin_amdgcn_perm(
            __float_as_uint(shi) + 0x8000u,
            __float_as_uint(slo) + 0x8000u, 0x07060302u);
        A[(p0 + pxl) * 100 + tl * 32 + c2] = (int)pk;
      }
    }
#pragma unroll 1
    for (int kk = 0; kk < 6; ++kk) {
      int4v av = *(const int4v*)&A[(p0 + n16) * 100 + kk * 16 + q * 4];
      short8 af = __builtin_bit_cast(short8, av);
      int g = chunk * 24 + kk * 4 + q;
#pragma unroll
      for (int nt = 0; nt < 4; ++nt) {
        int4v bv = *(const int4v*)&Bg[(g * 64 + nt * 16 + n16) * 4];
        short8 bfr = __builtin_bit_cast(short8, bv);
        acc[nt] = __builtin_amdgcn_mfma_f32_16x16x32_bf16(af, bfr, acc[nt], 0, 0, 0);
      }
    }
  }

  // ---------- epilogue: y store + stats (alias into own A region) ----------
  float* SW = (float*)&A[cg * 1600];
#pragma unroll
  for (int nt = 0; nt < 4; ++nt) {
    int o = nt * 16 + n16;
    float bv = dc_b[o];
    f32x4 r;
    float s = 0.0f, ss = 0.0f;
#pragma unroll
    for (int r0 = 0; r0 < 4; ++r0) {
      r[r0] = acc[nt][r0] + bv;
      s += r[r0];
      ss += r[r0] * r[r0];
    }
    *(f32x4*)(ybuf + (size_t)(b * OO + o) * HWSZ + hw0 + p0 + q * 4) = r;
    s += __shfl_xor(s, 16);  s += __shfl_xor(s, 32);
    ss += __shfl_xor(ss, 16); ss += __shfl_xor(ss, 32);
    if (lane < 16) {   // lane == n16
      SW[nt * 16 + lane] = s;
      SW[64 + nt * 16 + lane] = ss;
    }
  }
  __syncthreads();
  if (threadIdx.x < 64) {
    float ts = 0.0f, tq = 0.0f;
#pragma unroll
    for (int wv = 0; wv < 4; ++wv) {
      const float* Sv = (const float*)&A[wv * 1600];
      ts += Sv[threadIdx.x];
      tq += Sv[64 + threadIdx.x];
    }
    atomicAdd(&sums[threadIdx.x], ts);
    atomicAdd(&sumsq[threadIdx.x], tq);
  }
}

__global__ __launch_bounds__(256) void norm_kernel(
    const float* __restrict__ ybuf, const float* __restrict__ sums,
    const float* __restrict__ sumsq, const float* __restrict__ gamma,
    const float* __restrict__ beta, float* __restrict__ out) {
  int gid = blockIdx.x * 256 + threadIdx.x;
  int flat = gid << 2;
  int o = (flat >> 14) & 63;
  const float invN = 1.0f / (float)(BB * HWSZ);
  float mean = sums[o] * invN;
  float var = sumsq[o] * invN - mean * mean;
  float rstd = rsqrtf(var + 1e-5f);
  float g = gamma[o] * rstd;
  float bta = beta[o] - mean * g;
  float4 v = ((const float4*)ybuf)[gid];
  float4 r;
  r.x = fmaxf(v.x * g + bta, 0.0f);
  r.y = fmaxf(v.y * g + bta, 0.0f);
  r.z = fmaxf(v.z * g + bta, 0.0f);
  r.w = fmaxf(v.w * g + bta, 0.0f);
  ((float4*)out)[gid] = r;
}

extern "C" void kernel_launch(void* const* d_in, const int* in_sizes, int n_in,
                              void* d_out, int out_size, void* d_ws, size_t ws_size,
                              hipStream_t stream) {
  const float* x     = (const float*)d_in[0];
  const float* off_w = (const float*)d_in[1];
  const float* off_b = (const float*)d_in[2];
  const float* dc_w  = (const float*)d_in[3];
  const float* dc_b  = (const float*)d_in[4];
  const float* gamma = (const float*)d_in[5];
  const float* beta  = (const float*)d_in[6];
  float* ws = (float*)d_ws;
  int*   Bg     = (int*)(ws + WS_BG);
  int*   Bgo    = (int*)(ws + WS_BGO);
  float* sums   = ws + WS_SUMS;
  float* sumsq  = ws + WS_SUMSQ;
  float* ybuf   = ws + WS_YBUF;
  float* out = (float*)d_out;
  // d_out (16 MB fp32) doubles as NHWC-bf16 scratch (8 MB); dead until norm writes.
  unsigned int* xTu = (unsigned int*)d_out;

  prep_kernel<<<BB * HH + 64, 256, 0, stream>>>(x, off_w, dc_w, xTu, Bg, Bgo, sums);
  fused_kernel<<<BB * HWSZ / 64, 256, 0, stream>>>(xTu, Bg, Bgo, off_b, dc_b, ybuf, sums, sumsq);
  norm_kernel<<<BB * OO * HWSZ / (4 * 256), 256, 0, stream>>>(ybuf, sums, sumsq, gamma, beta, out);
}